// Round 13
// baseline (1105.655 us; speedup 1.0000x reference)
//
#include <hip/hip_runtime.h>
#include <hip/hip_bf16.h>

#define GN 50000
#define GE 800000
#define GH 4
#define GFH 32
#define GC 40
#define GIN 128

typedef __hip_bfloat16 bf16;
typedef __attribute__((ext_vector_type(8))) short bf16x8;
typedef __attribute__((ext_vector_type(4))) float f32x4;

// mode m: 0 = tensor stored as bf16, 1 = stored as fp32
static __device__ __forceinline__ float ldx(const void* p, size_t i, int m) {
    if (m) return ((const float*)p)[i];
    return __bfloat162float(((const bf16*)p)[i]);
}
static __device__ __forceinline__ void stx(void* p, size_t i, int m, float v) {
    if (m) ((float*)p)[i] = v;
    else ((bf16*)p)[i] = __float2bfloat16(v);
}
static __device__ __forceinline__ unsigned short f2bfu(float v) {
    union { bf16 b; unsigned short u; } cv;
    cv.b = __float2bfloat16(v);
    return cv.u;
}
static __device__ __forceinline__ float lo16(unsigned u) { return __uint_as_float(u << 16); }
static __device__ __forceinline__ float hi16(unsigned u) { return __uint_as_float(u & 0xFFFF0000u); }
static __device__ __forceinline__ float guard_finite(float v) {
    if (!(v == v) || fabsf(v) > 1e30f) return 0.f;
    return v;
}

// ---------------- dtype probe: fp32 misread as bf16 shows wild exponents ----------------
__global__ void detect_kernel(const unsigned short* __restrict__ f, int* __restrict__ flag) {
    int t = threadIdx.x;  // 256
    unsigned short u = f[t];
    int e = (u >> 7) & 0xFF;
    if (e >= 0x8E) atomicAdd(flag, 1);  // |val| >= 2^15 or inf/nan -> not sane bf16 data
}

__global__ void sentinel_kernel(unsigned short* __restrict__ o, int n) {
    int i = blockIdx.x * blockDim.x + threadIdx.x;
    if (i < n) o[i] = 0x3F80;  // bf16 1.0
}

// ---------------- CSR build ----------------
__global__ void count_kernel(const int* __restrict__ dst, int* __restrict__ deg, int n) {
    int e = blockIdx.x * blockDim.x + threadIdx.x;
    if (e < n) {
        int d = dst[e];
        if (d >= 0 && d < GN) atomicAdd(&deg[d], 1);
    }
}

__global__ void scan_kernel(const int* __restrict__ deg, int* __restrict__ indptr,
                            int* __restrict__ cursor, int n) {
    __shared__ int buf[1024];
    int tid = threadIdx.x;
    int running = 0;
    for (int base = 0; base < n; base += 1024) {
        int i = base + tid;
        int v = (i < n) ? deg[i] : 0;
        buf[tid] = v;
        __syncthreads();
        for (int off = 1; off < 1024; off <<= 1) {
            int t = (tid >= off) ? buf[tid - off] : 0;
            __syncthreads();
            buf[tid] += t;
            __syncthreads();
        }
        int inc = buf[tid];
        if (i < n) { indptr[i + 1] = running + inc; cursor[i] = running + inc - v; }
        running += buf[1023];
        __syncthreads();
    }
    if (tid == 0) indptr[0] = 0;
}

__global__ void scatter_kernel(const int* __restrict__ src, const int* __restrict__ dst,
                               int* __restrict__ cursor, int* __restrict__ csr_src, int n) {
    int e = blockIdx.x * blockDim.x + threadIdx.x;
    if (e < n) {
        int d = dst[e];
        if (d < 0 || d >= GN) return;
        int p = atomicAdd(&cursor[d], 1);
        if (p >= 0 && p < GE) csr_src[p] = src[e];
    }
}

// ---------------- w transpose: w[128][M] -> wt[M][128] (bf16 bits out) ----------------
__global__ void transpose_w(const void* __restrict__ w, unsigned short* __restrict__ wt, int M,
                            const int* __restrict__ flag) {
    int m = (*flag != 0) ? 1 : 0;
    int idx = blockIdx.x * blockDim.x + threadIdx.x;
    if (idx < 128 * M) {
        int k = idx / M, c = idx - k * M;
        wt[c * 128 + k] = f2bfu(ldx(w, idx, m));
    }
}

// ---------------- MFMA GEMM: Y[N,M](bf16) = X[N,128] @ W[128,M] ----------------
__global__ __launch_bounds__(256) void gemm_tile(const void* __restrict__ X, int xext,
                                                 const void* __restrict__ W,
                                                 bf16* __restrict__ Y, int nrows, int M,
                                                 const int* __restrict__ flag) {
    constexpr int LDX = 136;  // bf16 units; pad 8 -> 2-way LDS conflict only (free)
    __shared__ unsigned short Xs[64 * LDX];  // [r][k]
    __shared__ unsigned short Wt[64 * LDX];  // [c][k]
    int m = (*flag != 0) ? 1 : 0;
    int mx_ = xext ? m : 0;
    int tid = threadIdx.x;
    int rb = blockIdx.x * 64, cb = blockIdx.y * 64;

    for (int idx = tid; idx < 64 * 128; idx += 256) {
        int r = idx >> 7, k = idx & 127;
        int row = rb + r;
        Xs[r * LDX + k] =
            (row < nrows) ? f2bfu(ldx(X, (size_t)row * 128 + k, mx_)) : (unsigned short)0;
    }
    for (int idx = tid; idx < 128 * 64; idx += 256) {
        int k = idx >> 6, c = idx & 63;
        int col = cb + c;
        Wt[c * LDX + k] = (col < M) ? f2bfu(ldx(W, (size_t)k * M + col, m)) : (unsigned short)0;
    }
    __syncthreads();

    int wave = tid >> 6, lane = tid & 63;
    int lr = lane & 15, quad = lane >> 4;
    int mrow = wave * 16 + lr;

    f32x4 acc[4] = {};
    for (int kk = 0; kk < 128; kk += 32) {
        bf16x8 a = *(const bf16x8*)&Xs[mrow * LDX + kk + quad * 8];
#pragma unroll
        for (int nt = 0; nt < 4; nt++) {
            bf16x8 b = *(const bf16x8*)&Wt[(nt * 16 + lr) * LDX + kk + quad * 8];
            acc[nt] = __builtin_amdgcn_mfma_f32_16x16x32_bf16(a, b, acc[nt], 0, 0, 0);
        }
    }

    int drow = rb + wave * 16 + quad * 4;
#pragma unroll
    for (int nt = 0; nt < 4; nt++) {
        int col = cb + nt * 16 + lr;
#pragma unroll
        for (int i = 0; i < 4; i++) {
            int row = drow + i;
            if (row < nrows && col < M) Y[(size_t)row * M + col] = __float2bfloat16(acc[nt][i]);
        }
    }
}

// ---------------- MFMA in-place GEMM: X[nrows,128] <- X @ W[128,128] ----------------
__global__ __launch_bounds__(256) void gemm_inplace(bf16* __restrict__ X,
                                                    const void* __restrict__ W, int nrows,
                                                    const int* __restrict__ flag) {
    constexpr int LDX = 136;
    __shared__ unsigned short Xs[64 * LDX];    // [r][k]
    __shared__ unsigned short Wt[128 * LDX];   // [c][k]
    int m = (*flag != 0) ? 1 : 0;
    int tid = threadIdx.x;
    int rb = blockIdx.x * 64;

    for (int idx = tid; idx < 64 * 128; idx += 256) {
        int r = idx >> 7, k = idx & 127;
        int row = rb + r;
        Xs[r * LDX + k] =
            (row < nrows) ? ((const unsigned short*)X)[(size_t)row * 128 + k] : (unsigned short)0;
    }
    for (int idx = tid; idx < 128 * 128; idx += 256) {
        int k = idx >> 7, c = idx & 127;
        Wt[c * LDX + k] = f2bfu(ldx(W, (size_t)k * 128 + c, m));
    }
    __syncthreads();

    int wave = tid >> 6, lane = tid & 63;
    int lr = lane & 15, quad = lane >> 4;
    int mrow = wave * 16 + lr;

    f32x4 acc[8] = {};
    for (int kk = 0; kk < 128; kk += 32) {
        bf16x8 a = *(const bf16x8*)&Xs[mrow * LDX + kk + quad * 8];
#pragma unroll
        for (int nt = 0; nt < 8; nt++) {
            bf16x8 b = *(const bf16x8*)&Wt[(nt * 16 + lr) * LDX + kk + quad * 8];
            acc[nt] = __builtin_amdgcn_mfma_f32_16x16x32_bf16(a, b, acc[nt], 0, 0, 0);
        }
    }

    int drow = rb + wave * 16 + quad * 4;
#pragma unroll
    for (int nt = 0; nt < 8; nt++) {
        int col = nt * 16 + lr;
#pragma unroll
        for (int i = 0; i < 4; i++) {
            int row = drow + i;
            if (row < nrows) X[(size_t)row * 128 + col] = __float2bfloat16(acc[nt][i]);
        }
    }
}

// ---------------- el/er: [N,H] dot over F ----------------
__global__ void elr_kernel(const bf16* __restrict__ ft, const void* __restrict__ al,
                           const void* __restrict__ ar, float* __restrict__ el,
                           float* __restrict__ er, int n, int F, const int* __restrict__ flag) {
    int m = (*flag != 0) ? 1 : 0;
    int gid = blockIdx.x * blockDim.x + threadIdx.x;
    if (gid >= n * 4) return;
    int nid = gid >> 2, h = gid & 3;
    const bf16* f = ft + (size_t)nid * (4 * F) + h * F;
    float sl = 0.f, sr = 0.f;
    for (int i = 0; i < F; i++) {
        float v = __bfloat162float(f[i]);
        sl += v * ldx(al, h * F + i, m);
        sr += v * ldx(ar, h * F + i, m);
    }
    el[gid] = sl;
    er[gid] = sr;
}

// ---------------- per-dst softmax + aggregation (LDS-staged gather) ----------------
// Chunk of CH edges: (1) weights+indices to LDS, (2) cooperative coalesced staging of
// neighbor rows into LDS (independent loads, high MLP), (3) consume from LDS.
// Feature-pair + edge-parity ownership as round 11; merge logic unchanged.
template <int FTOT, bool FINAL>
__global__ __launch_bounds__(FINAL ? 192 : 128) void agg_kernel(
    const bf16* __restrict__ ft, const float* __restrict__ el, const float* __restrict__ er,
    const int* __restrict__ indptr, const int* __restrict__ csr_src,
    const void* __restrict__ bias, const void* __restrict__ h_in, int hext,
    const unsigned short* __restrict__ wt, const bf16* __restrict__ skip_pre,
    bf16* __restrict__ out, const void* __restrict__ bias_last, void* __restrict__ fout,
    const int* __restrict__ flag) {
    constexpr int CH = 32;
    constexpr int NT = FINAL ? 192 : 128;
    constexpr int FP = FTOT / 2;  // feature pairs
    constexpr int HF = FTOT / 4;  // head size
    constexpr int RW = FTOT / 2;  // uints per staged row
    int m = (*flag != 0) ? 1 : 0;
    int mh = hext ? m : 0;
    int v = blockIdx.x;
    int t = threadIdx.x;
    int beg = indptr[v], end = indptr[v + 1];
    beg = max(0, min(beg, GE));
    end = max(beg, min(end, GE));

    __shared__ float hv[128];
    __shared__ unsigned fts[CH * RW];  // staged neighbor rows (bf16 pairs)
    __shared__ float wbuf[CH * 4];
    __shared__ int ubuf[CH];
    __shared__ float red[128];
    __shared__ float s_sh[4];
    __shared__ float ovals[FINAL ? 160 : 1];
    __shared__ float lsm[FINAL ? 64 : 1];

    int g = (t < FTOT) ? (t / FP) : 0;
    int f = (t < FTOT) ? (t - g * FP) : 0;
    int c0 = 2 * f;
    int h0 = c0 / HF;

    float sk = 0.f;
    if (skip_pre == nullptr) {
        if (t < 128) hv[t] = ldx(h_in, (size_t)v * 128 + t, mh);
        __syncthreads();
        if (t < FTOT) {
            int row = c0 + g;
            const unsigned short* wr = wt + (size_t)row * 128;
            float p0 = 0.f, p1 = 0.f, p2 = 0.f, p3 = 0.f;
#pragma unroll 2
            for (int kb = 0; kb < 128; kb += 8) {
                uint4 wv = *(const uint4*)(wr + kb);
                float4 hA = *(const float4*)&hv[kb];
                float4 hB = *(const float4*)&hv[kb + 4];
                p0 += hA.x * lo16(wv.x) + hA.y * hi16(wv.x);
                p1 += hA.z * lo16(wv.y) + hA.w * hi16(wv.y);
                p2 += hB.x * lo16(wv.z) + hB.y * hi16(wv.z);
                p3 += hB.z * lo16(wv.w) + hB.w * hi16(wv.w);
            }
            sk = (p0 + p1) + (p2 + p3);
        }
    }
    float sk1_pre = 0.f;
    if (skip_pre != nullptr && t < FP) {
        unsigned pk = *(const unsigned*)(skip_pre + (size_t)v * FTOT + c0);
        sk = lo16(pk);
        sk1_pre = hi16(pk);
    }

    int h = t & 3, slot = t >> 2;
    float erv = er[v * 4 + h];
    float s_part = 0.f;
    float a0 = 0.f, a1 = 0.f;

    for (int cb = beg; cb < end; cb += CH) {
        int chn = min(CH, end - cb);
        int chn_pad = (chn + 7) & ~7;
        if (t < 128) {
            for (int j = slot; j < chn; j += 32) {
                int u = csr_src[cb + j];
                u = min(max(u, 0), GN - 1);
                if (h == 0) ubuf[j] = u;
                float e = el[u * 4 + h] + erv;
                e = e > 0.f ? e : 0.2f * e;
                float w = __expf(fminf(e, 60.f));
                wbuf[j * 4 + h] = w;
                s_part += w;
            }
        }
        for (int j = chn + t; j < chn_pad; j += NT) {
            ubuf[j] = 0;
            wbuf[j * 4 + 0] = 0.f;
            wbuf[j * 4 + 1] = 0.f;
            wbuf[j * 4 + 2] = 0.f;
            wbuf[j * 4 + 3] = 0.f;
        }
        __syncthreads();
        // stage rows cooperatively: fully independent coalesced loads
        for (int idx = t; idx < chn_pad * RW; idx += NT) {
            int j = idx / RW, c = idx - j * RW;
            fts[idx] = *(const unsigned*)(ft + (size_t)ubuf[j] * FTOT + 2 * c);
        }
        __syncthreads();
        if (t < FTOT) {
            for (int j = g; j < chn_pad; j += 8) {
                float w0 = wbuf[j * 4 + h0], w1 = wbuf[(j + 2) * 4 + h0];
                float w2 = wbuf[(j + 4) * 4 + h0], w3 = wbuf[(j + 6) * 4 + h0];
                unsigned p0 = fts[j * RW + f], p1 = fts[(j + 2) * RW + f];
                unsigned p2 = fts[(j + 4) * RW + f], p3 = fts[(j + 6) * RW + f];
                a0 += w0 * lo16(p0) + w1 * lo16(p1) + w2 * lo16(p2) + w3 * lo16(p3);
                a1 += w0 * hi16(p0) + w1 * hi16(p1) + w2 * hi16(p2) + w3 * hi16(p3);
            }
        }
        __syncthreads();
    }

    if (t < 128) red[t] = s_part;
    if (t < FTOT && g == 1) {
        wbuf[c0] = a0;
        wbuf[c0 + 1] = a1;
        if (FINAL) ((float*)fts)[f] = sk;  // group1's skip(2f+1) via staged buffer
    }
    __syncthreads();
    for (int off = 64; off >= 4; off >>= 1) {
        if (t < off) red[t] += red[t + off];
        __syncthreads();
    }
    if (t < 4) s_sh[t] = red[t];
    __syncthreads();

    if (t < FP) {
        float acc0 = a0 + wbuf[c0];
        float acc1 = a1 + wbuf[c0 + 1];
        float s0 = s_sh[h0];
        float r0 = (s0 > 0.f) ? acc0 / s0 : 0.f;
        float r1 = (s0 > 0.f) ? acc1 / s0 : 0.f;
        float skA = sk, skB;
        if (skip_pre != nullptr) skB = sk1_pre;
        else skB = FINAL ? ((float*)fts)[f] : 0.f;
        float o0 = r0 + ldx(bias, c0, m) + skA;
        float o1 = r1 + ldx(bias, c0 + 1, m) + skB;
        if constexpr (!FINAL) {
            unsigned pk = ((unsigned)f2bfu(guard_finite(o1)) << 16) |
                          (unsigned)f2bfu(guard_finite(o0));
            *(unsigned*)(out + (size_t)v * FTOT + c0) = pk;
        } else {
            ovals[c0] = o0;
            ovals[c0 + 1] = o1;
        }
    }

    if constexpr (FINAL) {
        __syncthreads();
        if (t < 40)
            lsm[t] = 0.25f * (ovals[t] + ovals[40 + t] + ovals[80 + t] + ovals[120 + t]) +
                     ldx(bias_last, t, m);
        __syncthreads();
        if (t < 64) {
            float x = (t < 40) ? lsm[t] : -3.0e38f;
            float mx = x;
            for (int off = 1; off < 64; off <<= 1) mx = fmaxf(mx, __shfl_xor(mx, off));
            float ex = (t < 40) ? __expf(x - mx) : 0.f;
            float sum = ex;
            for (int off = 1; off < 64; off <<= 1) sum += __shfl_xor(sum, off);
            if (t < 40) stx(fout, (size_t)v * 40 + t, m, guard_finite(x - mx - __logf(sum)));
        }
    }
}

// ---------------- BatchNorm (+ ReLU) on bf16 [N,128] ----------------
__global__ void bn_stats(const bf16* __restrict__ x, float* __restrict__ gsum,
                         float* __restrict__ gsq, int n) {
    int c = threadIdx.x;  // 128
    int rows_per_block = (n + gridDim.x - 1) / gridDim.x;
    int r0 = blockIdx.x * rows_per_block;
    int r1 = min(n, r0 + rows_per_block);
    float s = 0.f, q = 0.f;
    for (int r = r0; r < r1; r++) {
        float v = __bfloat162float(x[(size_t)r * 128 + c]);
        s += v;
        q += v * v;
    }
    atomicAdd(&gsum[c], s);
    atomicAdd(&gsq[c], q);
}

__global__ void bn_apply(bf16* __restrict__ x, const float* __restrict__ gsum,
                         const float* __restrict__ gsq, const void* __restrict__ g,
                         const void* __restrict__ be, int n, const int* __restrict__ flag) {
    int m = (*flag != 0) ? 1 : 0;
    int gid = blockIdx.x * blockDim.x + threadIdx.x;
    if (gid >= n * 128) return;
    int c = gid & 127;
    float inv_n = 1.f / (float)n;
    float mu = gsum[c] * inv_n;
    float var = gsq[c] * inv_n - mu * mu;
    float y = (__bfloat162float(x[gid]) - mu) * rsqrtf(fmaxf(var, 0.f) + 1e-5f) * ldx(g, c, m) +
              ldx(be, c, m);
    x[gid] = __float2bfloat16(y > 0.f ? y : 0.f);
}

extern "C" void kernel_launch(void* const* d_in, const int* in_sizes, int n_in,
                              void* d_out, int out_size, void* d_ws, size_t ws_size,
                              hipStream_t stream) {
    const void* feat = d_in[0];
    const int* src = (const int*)d_in[1];
    const int* dst = (const int*)d_in[2];
    const void* w_fc0 = d_in[3];
    const void* al0 = d_in[4];
    const void* ar0 = d_in[5];
    const void* b0 = d_in[6];
    const void* w_lin0 = d_in[7];
    const void* g0 = d_in[8];
    const void* be0 = d_in[9];
    const void* w_fc1 = d_in[10];
    const void* al1 = d_in[11];
    const void* ar1 = d_in[12];
    const void* b1 = d_in[13];
    const void* w_lin1 = d_in[14];
    const void* g1 = d_in[15];
    const void* be1 = d_in[16];
    const void* w_fc2 = d_in[17];
    const void* al2 = d_in[18];
    const void* ar2 = d_in[19];
    const void* b2 = d_in[20];
    const void* w_lin2 = d_in[21];
    const void* bias_last = d_in[22];

    // ---- workspace guard: total need ~34.4 MB ----
    if (ws_size < 35000000) {
        sentinel_kernel<<<(out_size + 255) / 256, 256, 0, stream>>>((unsigned short*)d_out,
                                                                    out_size);
        return;
    }

    char* p = (char*)d_ws;
    auto alloc = [&](size_t bytes) {
        char* r = p;
        p += (bytes + 255) & ~(size_t)255;
        return r;
    };
    bf16* ftb = (bf16*)alloc((size_t)GN * 160 * 2);   // 16.0 MB
    bf16* hbuf = (bf16*)alloc((size_t)GN * 128 * 2);  // 12.8 MB
    float* elb = (float*)alloc((size_t)GN * 4 * 4);   // 0.8 MB
    float* erb = (float*)alloc((size_t)GN * 4 * 4);   // 0.8 MB
    int* indptr = (int*)alloc((size_t)(GN + 1) * 4);
    int* cursor = (int*)alloc((size_t)GN * 4);
    unsigned short* wt2 = (unsigned short*)alloc(160 * 128 * 2);  // 40 KB
    char* zbase = p;  // ---- zero-initialized region ----
    int* deg = (int*)alloc((size_t)GN * 4);
    int* csr = (int*)alloc((size_t)GE * 4);  // 3.2 MB
    float* gs0 = (float*)alloc(128 * 4);
    float* gq0 = (float*)alloc(128 * 4);
    float* gs1 = (float*)alloc(128 * 4);
    float* gq1 = (float*)alloc(128 * 4);
    int* flag = (int*)alloc(4);
    hipMemsetAsync(zbase, 0, (size_t)(p - zbase), stream);

    detect_kernel<<<1, 256, 0, stream>>>((const unsigned short*)feat, flag);

    // CSR build + weight transpose (independent, early)
    count_kernel<<<(GE + 255) / 256, 256, 0, stream>>>(dst, deg, GE);
    scan_kernel<<<1, 1024, 0, stream>>>(deg, indptr, cursor, GN);
    scatter_kernel<<<(GE + 255) / 256, 256, 0, stream>>>(src, dst, cursor, csr, GE);
    transpose_w<<<80, 256, 0, stream>>>(w_lin2, wt2, 160, flag);

    dim3 g2(782, 2), g3(782, 3);

    // ----- Layer 0 -----
    gemm_tile<<<g2, 256, 0, stream>>>(feat, 1, w_fc0, ftb, GN, 128, flag);
    gemm_tile<<<g2, 256, 0, stream>>>(feat, 1, w_lin0, hbuf, GN, 128, flag);  // skip0 -> hbuf
    elr_kernel<<<(GN * 4 + 255) / 256, 256, 0, stream>>>(ftb, al0, ar0, elb, erb, GN, 32, flag);
    agg_kernel<128, false><<<GN, 128, 0, stream>>>(ftb, elb, erb, indptr, csr, b0, feat, 1,
                                                   nullptr, hbuf, hbuf, nullptr, nullptr, flag);
    bn_stats<<<256, 128, 0, stream>>>(hbuf, gs0, gq0, GN);
    bn_apply<<<(GN * 128 + 255) / 256, 256, 0, stream>>>(hbuf, gs0, gq0, g0, be0, GN, flag);

    // ----- Layer 1 (h updated in place) -----
    gemm_tile<<<g2, 256, 0, stream>>>(hbuf, 0, w_fc1, ftb, GN, 128, flag);
    elr_kernel<<<(GN * 4 + 255) / 256, 256, 0, stream>>>(ftb, al1, ar1, elb, erb, GN, 32, flag);
    gemm_inplace<<<782, 256, 0, stream>>>(hbuf, w_lin1, GN, flag);  // hbuf <- h1 @ w_lin1
    agg_kernel<128, false><<<GN, 128, 0, stream>>>(ftb, elb, erb, indptr, csr, b1, hbuf, 0,
                                                   nullptr, hbuf, hbuf, nullptr, nullptr, flag);
    bn_stats<<<256, 128, 0, stream>>>(hbuf, gs1, gq1, GN);
    bn_apply<<<(GN * 128 + 255) / 256, 256, 0, stream>>>(hbuf, gs1, gq1, g1, be1, GN, flag);

    // ----- Layer 2 (final; 192 threads, feature-pair + edge-parity) -----
    gemm_tile<<<g3, 256, 0, stream>>>(hbuf, 0, w_fc2, ftb, GN, 160, flag);
    elr_kernel<<<(GN * 4 + 255) / 256, 256, 0, stream>>>(ftb, al2, ar2, elb, erb, GN, 40, flag);
    agg_kernel<160, true><<<GN, 192, 0, stream>>>(ftb, elb, erb, indptr, csr, b2, hbuf, 0,
                                                  wt2, nullptr, nullptr, bias_last, d_out, flag);
}

// Round 14
// 906.642 us; speedup vs baseline: 1.2195x; 1.2195x over previous
//
#include <hip/hip_runtime.h>
#include <hip/hip_bf16.h>

#define GN 50000
#define GE 800000
#define GH 4
#define GFH 32
#define GC 40
#define GIN 128

typedef __hip_bfloat16 bf16;
typedef __attribute__((ext_vector_type(8))) short bf16x8;
typedef __attribute__((ext_vector_type(4))) float f32x4;

// mode m: 0 = tensor stored as bf16, 1 = stored as fp32
static __device__ __forceinline__ float ldx(const void* p, size_t i, int m) {
    if (m) return ((const float*)p)[i];
    return __bfloat162float(((const bf16*)p)[i]);
}
static __device__ __forceinline__ void stx(void* p, size_t i, int m, float v) {
    if (m) ((float*)p)[i] = v;
    else ((bf16*)p)[i] = __float2bfloat16(v);
}
static __device__ __forceinline__ unsigned short f2bfu(float v) {
    union { bf16 b; unsigned short u; } cv;
    cv.b = __float2bfloat16(v);
    return cv.u;
}
static __device__ __forceinline__ float lo16(unsigned u) { return __uint_as_float(u << 16); }
static __device__ __forceinline__ float hi16(unsigned u) { return __uint_as_float(u & 0xFFFF0000u); }
static __device__ __forceinline__ float guard_finite(float v) {
    if (!(v == v) || fabsf(v) > 1e30f) return 0.f;
    return v;
}

// ---------------- dtype probe: fp32 misread as bf16 shows wild exponents ----------------
__global__ void detect_kernel(const unsigned short* __restrict__ f, int* __restrict__ flag) {
    int t = threadIdx.x;  // 256
    unsigned short u = f[t];
    int e = (u >> 7) & 0xFF;
    if (e >= 0x8E) atomicAdd(flag, 1);  // |val| >= 2^15 or inf/nan -> not sane bf16 data
}

__global__ void sentinel_kernel(unsigned short* __restrict__ o, int n) {
    int i = blockIdx.x * blockDim.x + threadIdx.x;
    if (i < n) o[i] = 0x3F80;  // bf16 1.0
}

// ---------------- CSR build ----------------
__global__ void count_kernel(const int* __restrict__ dst, int* __restrict__ deg, int n) {
    int e = blockIdx.x * blockDim.x + threadIdx.x;
    if (e < n) {
        int d = dst[e];
        if (d >= 0 && d < GN) atomicAdd(&deg[d], 1);
    }
}

__global__ void scan_kernel(const int* __restrict__ deg, int* __restrict__ indptr,
                            int* __restrict__ cursor, int n) {
    __shared__ int buf[1024];
    int tid = threadIdx.x;
    int running = 0;
    for (int base = 0; base < n; base += 1024) {
        int i = base + tid;
        int v = (i < n) ? deg[i] : 0;
        buf[tid] = v;
        __syncthreads();
        for (int off = 1; off < 1024; off <<= 1) {
            int t = (tid >= off) ? buf[tid - off] : 0;
            __syncthreads();
            buf[tid] += t;
            __syncthreads();
        }
        int inc = buf[tid];
        if (i < n) { indptr[i + 1] = running + inc; cursor[i] = running + inc - v; }
        running += buf[1023];
        __syncthreads();
    }
    if (tid == 0) indptr[0] = 0;
}

__global__ void scatter_kernel(const int* __restrict__ src, const int* __restrict__ dst,
                               int* __restrict__ cursor, int* __restrict__ csr_src, int n) {
    int e = blockIdx.x * blockDim.x + threadIdx.x;
    if (e < n) {
        int d = dst[e];
        if (d < 0 || d >= GN) return;
        int p = atomicAdd(&cursor[d], 1);
        if (p >= 0 && p < GE) csr_src[p] = src[e];
    }
}

// ---------------- w-mean: wmt[c][128] (c<48, zero-pad c>=40) = mean_h w_lin2[k][h*40+c] ----------------
__global__ void wmean_kernel(const void* __restrict__ w, unsigned short* __restrict__ wmt,
                             const int* __restrict__ flag) {
    int m = (*flag != 0) ? 1 : 0;
    int idx = blockIdx.x * blockDim.x + threadIdx.x;
    if (idx < 48 * 128) {
        int c = idx >> 7, k = idx & 127;
        float s = 0.f;
        if (c < 40) {
            s = 0.25f * (ldx(w, (size_t)k * 160 + c, m) + ldx(w, (size_t)k * 160 + 40 + c, m) +
                         ldx(w, (size_t)k * 160 + 80 + c, m) + ldx(w, (size_t)k * 160 + 120 + c, m));
        }
        wmt[c * 128 + k] = f2bfu(s);
    }
}

// ---------------- MFMA GEMM: Y[N,M](bf16) = X[N,128] @ W[128,M] ----------------
__global__ __launch_bounds__(256) void gemm_tile(const void* __restrict__ X, int xext,
                                                 const void* __restrict__ W,
                                                 bf16* __restrict__ Y, int nrows, int M,
                                                 const int* __restrict__ flag) {
    constexpr int LDX = 136;  // bf16 units; pad 8 -> 2-way LDS conflict only (free)
    __shared__ unsigned short Xs[64 * LDX];  // [r][k]
    __shared__ unsigned short Wt[64 * LDX];  // [c][k]
    int m = (*flag != 0) ? 1 : 0;
    int mx_ = xext ? m : 0;
    int tid = threadIdx.x;
    int rb = blockIdx.x * 64, cb = blockIdx.y * 64;

    for (int idx = tid; idx < 64 * 128; idx += 256) {
        int r = idx >> 7, k = idx & 127;
        int row = rb + r;
        Xs[r * LDX + k] =
            (row < nrows) ? f2bfu(ldx(X, (size_t)row * 128 + k, mx_)) : (unsigned short)0;
    }
    for (int idx = tid; idx < 128 * 64; idx += 256) {
        int k = idx >> 6, c = idx & 63;
        int col = cb + c;
        Wt[c * LDX + k] = (col < M) ? f2bfu(ldx(W, (size_t)k * M + col, m)) : (unsigned short)0;
    }
    __syncthreads();

    int wave = tid >> 6, lane = tid & 63;
    int lr = lane & 15, quad = lane >> 4;
    int mrow = wave * 16 + lr;

    f32x4 acc[4] = {};
    for (int kk = 0; kk < 128; kk += 32) {
        bf16x8 a = *(const bf16x8*)&Xs[mrow * LDX + kk + quad * 8];
#pragma unroll
        for (int nt = 0; nt < 4; nt++) {
            bf16x8 b = *(const bf16x8*)&Wt[(nt * 16 + lr) * LDX + kk + quad * 8];
            acc[nt] = __builtin_amdgcn_mfma_f32_16x16x32_bf16(a, b, acc[nt], 0, 0, 0);
        }
    }

    int drow = rb + wave * 16 + quad * 4;
#pragma unroll
    for (int nt = 0; nt < 4; nt++) {
        int col = cb + nt * 16 + lr;
#pragma unroll
        for (int i = 0; i < 4; i++) {
            int row = drow + i;
            if (row < nrows && col < M) Y[(size_t)row * M + col] = __float2bfloat16(acc[nt][i]);
        }
    }
}

// ---------------- MFMA in-place GEMM: X[nrows,128] <- X @ W[128,128] ----------------
__global__ __launch_bounds__(256) void gemm_inplace(bf16* __restrict__ X,
                                                    const void* __restrict__ W, int nrows,
                                                    const int* __restrict__ flag) {
    constexpr int LDX = 136;
    __shared__ unsigned short Xs[64 * LDX];    // [r][k]
    __shared__ unsigned short Wt[128 * LDX];   // [c][k]
    int m = (*flag != 0) ? 1 : 0;
    int tid = threadIdx.x;
    int rb = blockIdx.x * 64;

    for (int idx = tid; idx < 64 * 128; idx += 256) {
        int r = idx >> 7, k = idx & 127;
        int row = rb + r;
        Xs[r * LDX + k] =
            (row < nrows) ? ((const unsigned short*)X)[(size_t)row * 128 + k] : (unsigned short)0;
    }
    for (int idx = tid; idx < 128 * 128; idx += 256) {
        int k = idx >> 7, c = idx & 127;
        Wt[c * LDX + k] = f2bfu(ldx(W, (size_t)k * 128 + c, m));
    }
    __syncthreads();

    int wave = tid >> 6, lane = tid & 63;
    int lr = lane & 15, quad = lane >> 4;
    int mrow = wave * 16 + lr;

    f32x4 acc[8] = {};
    for (int kk = 0; kk < 128; kk += 32) {
        bf16x8 a = *(const bf16x8*)&Xs[mrow * LDX + kk + quad * 8];
#pragma unroll
        for (int nt = 0; nt < 8; nt++) {
            bf16x8 b = *(const bf16x8*)&Wt[(nt * 16 + lr) * LDX + kk + quad * 8];
            acc[nt] = __builtin_amdgcn_mfma_f32_16x16x32_bf16(a, b, acc[nt], 0, 0, 0);
        }
    }

    int drow = rb + wave * 16 + quad * 4;
#pragma unroll
    for (int nt = 0; nt < 8; nt++) {
        int col = nt * 16 + lr;
#pragma unroll
        for (int i = 0; i < 4; i++) {
            int row = drow + i;
            if (row < nrows) X[(size_t)row * 128 + col] = __float2bfloat16(acc[nt][i]);
        }
    }
}

// ---------------- skipmean in-place: X[:,0:40] <- X @ wmt^T (wmt: [48][128]) ----------------
// Row-exclusive blocks: stage own 64 rows (full 128 wide) to LDS first, then overwrite cols<40.
__global__ __launch_bounds__(256) void skipmean_inplace(bf16* __restrict__ X,
                                                        const unsigned short* __restrict__ wmt,
                                                        int nrows) {
    constexpr int LDX = 136;
    __shared__ unsigned short Xs[64 * LDX];  // [r][k]
    __shared__ unsigned short Wt[48 * LDX];  // [c][k]
    int tid = threadIdx.x;
    int rb = blockIdx.x * 64;

    for (int idx = tid; idx < 64 * 128; idx += 256) {
        int r = idx >> 7, k = idx & 127;
        int row = rb + r;
        Xs[r * LDX + k] =
            (row < nrows) ? ((const unsigned short*)X)[(size_t)row * 128 + k] : (unsigned short)0;
    }
    for (int idx = tid; idx < 48 * 128; idx += 256) {
        int c = idx >> 7, k = idx & 127;
        Wt[c * LDX + k] = wmt[c * 128 + k];
    }
    __syncthreads();

    int wave = tid >> 6, lane = tid & 63;
    int lr = lane & 15, quad = lane >> 4;
    int mrow = wave * 16 + lr;

    f32x4 acc[3] = {};
    for (int kk = 0; kk < 128; kk += 32) {
        bf16x8 a = *(const bf16x8*)&Xs[mrow * LDX + kk + quad * 8];
#pragma unroll
        for (int nt = 0; nt < 3; nt++) {
            bf16x8 b = *(const bf16x8*)&Wt[(nt * 16 + lr) * LDX + kk + quad * 8];
            acc[nt] = __builtin_amdgcn_mfma_f32_16x16x32_bf16(a, b, acc[nt], 0, 0, 0);
        }
    }

    int drow = rb + wave * 16 + quad * 4;
#pragma unroll
    for (int nt = 0; nt < 3; nt++) {
        int col = nt * 16 + lr;
        if (col < 40) {
#pragma unroll
            for (int i = 0; i < 4; i++) {
                int row = drow + i;
                if (row < nrows) X[(size_t)row * 128 + col] = __float2bfloat16(acc[nt][i]);
            }
        }
    }
}

// ---------------- el/er: [N,H] dot over F ----------------
__global__ void elr_kernel(const bf16* __restrict__ ft, const void* __restrict__ al,
                           const void* __restrict__ ar, float* __restrict__ el,
                           float* __restrict__ er, int n, int F, const int* __restrict__ flag) {
    int m = (*flag != 0) ? 1 : 0;
    int gid = blockIdx.x * blockDim.x + threadIdx.x;
    if (gid >= n * 4) return;
    int nid = gid >> 2, h = gid & 3;
    const bf16* f = ft + (size_t)nid * (4 * F) + h * F;
    float sl = 0.f, sr = 0.f;
    for (int i = 0; i < F; i++) {
        float v = __bfloat162float(f[i]);
        sl += v * ldx(al, h * F + i, m);
        sr += v * ldx(ar, h * F + i, m);
    }
    el[gid] = sl;
    er[gid] = sr;
}

// ---------------- per-dst softmax + aggregation ----------------
// r12 gather structure (feature-pair + edge-parity); shuffle-based s reduction (1 barrier);
// non-FINAL: skip precomputed in skip_pre (pair read).  FINAL: head-averaged skip precomputed
// into h_in[:,0:40] by skipmean_inplace; added in the epilogue.
// out may alias skip_pre buffer: block v reads only row v, writes row v last.
template <int FTOT, bool FINAL>
__global__ __launch_bounds__(FINAL ? 192 : 128) void agg_kernel(
    const bf16* __restrict__ ft, const float* __restrict__ el, const float* __restrict__ er,
    const int* __restrict__ indptr, const int* __restrict__ csr_src,
    const void* __restrict__ bias, const void* __restrict__ h_in,
    const bf16* __restrict__ skip_pre, bf16* __restrict__ out,
    const void* __restrict__ bias_last, void* __restrict__ fout,
    const int* __restrict__ flag) {
    constexpr int CH = 128;
    constexpr int NT = FINAL ? 192 : 128;
    constexpr int FP = FTOT / 2;  // feature pairs
    constexpr int HF = FTOT / 4;  // head size
    int m = (*flag != 0) ? 1 : 0;
    int v = blockIdx.x;
    int t = threadIdx.x;
    int beg = indptr[v], end = indptr[v + 1];
    beg = max(0, min(beg, GE));
    end = max(beg, min(end, GE));

    __shared__ float wbuf[CH * 4];  // per-edge weights (4 heads); reused as merge buffer
    __shared__ int ubuf[CH];
    __shared__ float red[8];
    __shared__ float ovals[FINAL ? 160 : 1];
    __shared__ float lsm[FINAL ? 64 : 1];

    int g = (t < FTOT) ? (t / FP) : 0;
    int f = (t < FTOT) ? (t - g * FP) : 0;
    int c0 = 2 * f;
    int h0 = c0 / HF;

    float sk = 0.f, sk1_pre = 0.f;
    if (!FINAL && t < FP) {
        unsigned pk = *(const unsigned*)(skip_pre + (size_t)v * FTOT + c0);
        sk = lo16(pk);
        sk1_pre = hi16(pk);
    }

    int h = t & 3, slot = t >> 2;
    float erv = er[v * 4 + h];
    float s_part = 0.f;
    float a0 = 0.f, a1 = 0.f;

    for (int cb = beg; cb < end; cb += CH) {
        int chn = min(CH, end - cb);
        int chn_pad = (chn + 7) & ~7;
        if (t < 128) {
            for (int j = slot; j < chn; j += 32) {
                int u = csr_src[cb + j];
                u = min(max(u, 0), GN - 1);
                if (h == 0) ubuf[j] = u;
                float e = el[u * 4 + h] + erv;
                e = e > 0.f ? e : 0.2f * e;
                float w = __expf(fminf(e, 60.f));
                wbuf[j * 4 + h] = w;
                s_part += w;
            }
        }
        for (int j = chn + t; j < chn_pad; j += NT) {
            ubuf[j] = 0;
            wbuf[j * 4 + 0] = 0.f;
            wbuf[j * 4 + 1] = 0.f;
            wbuf[j * 4 + 2] = 0.f;
            wbuf[j * 4 + 3] = 0.f;
        }
        __syncthreads();
        if (t < FTOT) {
            for (int j = g; j < chn_pad; j += 8) {
                float w0 = wbuf[j * 4 + h0], w1 = wbuf[(j + 2) * 4 + h0];
                float w2 = wbuf[(j + 4) * 4 + h0], w3 = wbuf[(j + 6) * 4 + h0];
                int u0 = ubuf[j], u1 = ubuf[j + 2], u2 = ubuf[j + 4], u3 = ubuf[j + 6];
                unsigned p0 = *(const unsigned*)(ft + (size_t)u0 * FTOT + c0);
                unsigned p1 = *(const unsigned*)(ft + (size_t)u1 * FTOT + c0);
                unsigned p2 = *(const unsigned*)(ft + (size_t)u2 * FTOT + c0);
                unsigned p3 = *(const unsigned*)(ft + (size_t)u3 * FTOT + c0);
                a0 += w0 * lo16(p0) + w1 * lo16(p1) + w2 * lo16(p2) + w3 * lo16(p3);
                a1 += w0 * hi16(p0) + w1 * hi16(p1) + w2 * hi16(p2) + w3 * hi16(p3);
            }
        }
        __syncthreads();
    }

    // per-wave butterfly over slot bits (head preserved in lane&3), 1 barrier total
    if (t < 128) {
#pragma unroll
        for (int off = 4; off < 64; off <<= 1) s_part += __shfl_xor(s_part, off);
        if ((t & 63) < 4) red[((t >> 6) << 2) | (t & 3)] = s_part;
    }
    if (t < FTOT && g == 1) {
        wbuf[c0] = a0;
        wbuf[c0 + 1] = a1;
    }
    __syncthreads();

    if (t < FP) {
        float s0 = red[h0] + red[4 + h0];
        float acc0 = a0 + wbuf[c0];
        float acc1 = a1 + wbuf[c0 + 1];
        float r0 = (s0 > 0.f) ? acc0 / s0 : 0.f;
        float r1 = (s0 > 0.f) ? acc1 / s0 : 0.f;
        float o0 = r0 + ldx(bias, c0, m) + sk;
        float o1 = r1 + ldx(bias, c0 + 1, m) + sk1_pre;
        if constexpr (!FINAL) {
            unsigned pk = ((unsigned)f2bfu(guard_finite(o1)) << 16) |
                          (unsigned)f2bfu(guard_finite(o0));
            *(unsigned*)(out + (size_t)v * FTOT + c0) = pk;
        } else {
            ovals[c0] = o0;
            ovals[c0 + 1] = o1;
        }
    }

    if constexpr (FINAL) {
        __syncthreads();
        if (t < 40) {
            float sm = ldx(h_in, (size_t)v * 128 + t, 0);  // head-averaged skip (bf16)
            lsm[t] = 0.25f * (ovals[t] + ovals[40 + t] + ovals[80 + t] + ovals[120 + t]) + sm +
                     ldx(bias_last, t, m);
        }
        __syncthreads();
        if (t < 64) {
            float x = (t < 40) ? lsm[t] : -3.0e38f;
            float mx = x;
            for (int off = 1; off < 64; off <<= 1) mx = fmaxf(mx, __shfl_xor(mx, off));
            float ex = (t < 40) ? __expf(x - mx) : 0.f;
            float sum = ex;
            for (int off = 1; off < 64; off <<= 1) sum += __shfl_xor(sum, off);
            if (t < 40) stx(fout, (size_t)v * 40 + t, m, guard_finite(x - mx - __logf(sum)));
        }
    }
}

// ---------------- BatchNorm (+ ReLU) on bf16 [N,128] ----------------
__global__ void bn_stats(const bf16* __restrict__ x, float* __restrict__ gsum,
                         float* __restrict__ gsq, int n) {
    int c = threadIdx.x;  // 128
    int rows_per_block = (n + gridDim.x - 1) / gridDim.x;
    int r0 = blockIdx.x * rows_per_block;
    int r1 = min(n, r0 + rows_per_block);
    float s = 0.f, q = 0.f;
    for (int r = r0; r < r1; r++) {
        float v = __bfloat162float(x[(size_t)r * 128 + c]);
        s += v;
        q += v * v;
    }
    atomicAdd(&gsum[c], s);
    atomicAdd(&gsq[c], q);
}

__global__ void bn_apply(bf16* __restrict__ x, const float* __restrict__ gsum,
                         const float* __restrict__ gsq, const void* __restrict__ g,
                         const void* __restrict__ be, int n, const int* __restrict__ flag) {
    int m = (*flag != 0) ? 1 : 0;
    int gid = blockIdx.x * blockDim.x + threadIdx.x;
    if (gid >= n * 128) return;
    int c = gid & 127;
    float inv_n = 1.f / (float)n;
    float mu = gsum[c] * inv_n;
    float var = gsq[c] * inv_n - mu * mu;
    float y = (__bfloat162float(x[gid]) - mu) * rsqrtf(fmaxf(var, 0.f) + 1e-5f) * ldx(g, c, m) +
              ldx(be, c, m);
    x[gid] = __float2bfloat16(y > 0.f ? y : 0.f);
}

extern "C" void kernel_launch(void* const* d_in, const int* in_sizes, int n_in,
                              void* d_out, int out_size, void* d_ws, size_t ws_size,
                              hipStream_t stream) {
    const void* feat = d_in[0];
    const int* src = (const int*)d_in[1];
    const int* dst = (const int*)d_in[2];
    const void* w_fc0 = d_in[3];
    const void* al0 = d_in[4];
    const void* ar0 = d_in[5];
    const void* b0 = d_in[6];
    const void* w_lin0 = d_in[7];
    const void* g0 = d_in[8];
    const void* be0 = d_in[9];
    const void* w_fc1 = d_in[10];
    const void* al1 = d_in[11];
    const void* ar1 = d_in[12];
    const void* b1 = d_in[13];
    const void* w_lin1 = d_in[14];
    const void* g1 = d_in[15];
    const void* be1 = d_in[16];
    const void* w_fc2 = d_in[17];
    const void* al2 = d_in[18];
    const void* ar2 = d_in[19];
    const void* b2 = d_in[20];
    const void* w_lin2 = d_in[21];
    const void* bias_last = d_in[22];

    // ---- workspace guard: total need ~34.4 MB ----
    if (ws_size < 35000000) {
        sentinel_kernel<<<(out_size + 255) / 256, 256, 0, stream>>>((unsigned short*)d_out,
                                                                    out_size);
        return;
    }

    char* p = (char*)d_ws;
    auto alloc = [&](size_t bytes) {
        char* r = p;
        p += (bytes + 255) & ~(size_t)255;
        return r;
    };
    bf16* ftb = (bf16*)alloc((size_t)GN * 160 * 2);   // 16.0 MB
    bf16* hbuf = (bf16*)alloc((size_t)GN * 128 * 2);  // 12.8 MB
    float* elb = (float*)alloc((size_t)GN * 4 * 4);   // 0.8 MB
    float* erb = (float*)alloc((size_t)GN * 4 * 4);   // 0.8 MB
    int* indptr = (int*)alloc((size_t)(GN + 1) * 4);
    int* cursor = (int*)alloc((size_t)GN * 4);
    unsigned short* wmt = (unsigned short*)alloc(48 * 128 * 2);  // 12.3 KB
    char* zbase = p;  // ---- zero-initialized region ----
    int* deg = (int*)alloc((size_t)GN * 4);
    int* csr = (int*)alloc((size_t)GE * 4);  // 3.2 MB
    float* gs0 = (float*)alloc(128 * 4);
    float* gq0 = (float*)alloc(128 * 4);
    float* gs1 = (float*)alloc(128 * 4);
    float* gq1 = (float*)alloc(128 * 4);
    int* flag = (int*)alloc(4);
    hipMemsetAsync(zbase, 0, (size_t)(p - zbase), stream);

    detect_kernel<<<1, 256, 0, stream>>>((const unsigned short*)feat, flag);

    // CSR build + w-mean precompute (independent, early)
    count_kernel<<<(GE + 255) / 256, 256, 0, stream>>>(dst, deg, GE);
    scan_kernel<<<1, 1024, 0, stream>>>(deg, indptr, cursor, GN);
    scatter_kernel<<<(GE + 255) / 256, 256, 0, stream>>>(src, dst, cursor, csr, GE);
    wmean_kernel<<<24, 256, 0, stream>>>(w_lin2, wmt, flag);

    dim3 g2(782, 2), g3(782, 3);

    // ----- Layer 0 -----
    gemm_tile<<<g2, 256, 0, stream>>>(feat, 1, w_fc0, ftb, GN, 128, flag);
    gemm_tile<<<g2, 256, 0, stream>>>(feat, 1, w_lin0, hbuf, GN, 128, flag);  // skip0 -> hbuf
    elr_kernel<<<(GN * 4 + 255) / 256, 256, 0, stream>>>(ftb, al0, ar0, elb, erb, GN, 32, flag);
    agg_kernel<128, false><<<GN, 128, 0, stream>>>(ftb, elb, erb, indptr, csr, b0, nullptr,
                                                   hbuf, hbuf, nullptr, nullptr, flag);
    bn_stats<<<256, 128, 0, stream>>>(hbuf, gs0, gq0, GN);
    bn_apply<<<(GN * 128 + 255) / 256, 256, 0, stream>>>(hbuf, gs0, gq0, g0, be0, GN, flag);

    // ----- Layer 1 (h updated in place) -----
    gemm_tile<<<g2, 256, 0, stream>>>(hbuf, 0, w_fc1, ftb, GN, 128, flag);
    elr_kernel<<<(GN * 4 + 255) / 256, 256, 0, stream>>>(ftb, al1, ar1, elb, erb, GN, 32, flag);
    gemm_inplace<<<782, 256, 0, stream>>>(hbuf, w_lin1, GN, flag);  // hbuf <- h1 @ w_lin1
    agg_kernel<128, false><<<GN, 128, 0, stream>>>(ftb, elb, erb, indptr, csr, b1, nullptr,
                                                   hbuf, hbuf, nullptr, nullptr, flag);
    bn_stats<<<256, 128, 0, stream>>>(hbuf, gs1, gq1, GN);
    bn_apply<<<(GN * 128 + 255) / 256, 256, 0, stream>>>(hbuf, gs1, gq1, g1, be1, GN, flag);

    // ----- Layer 2 (final) -----
    gemm_tile<<<g3, 256, 0, stream>>>(hbuf, 0, w_fc2, ftb, GN, 160, flag);
    elr_kernel<<<(GN * 4 + 255) / 256, 256, 0, stream>>>(ftb, al2, ar2, elb, erb, GN, 40, flag);
    skipmean_inplace<<<782, 256, 0, stream>>>(hbuf, wmt, GN);  // hbuf[:,0:40] <- h2 @ wmean
    agg_kernel<160, true><<<GN, 192, 0, stream>>>(ftb, elb, erb, indptr, csr, b2, hbuf,
                                                  nullptr, nullptr, bias_last, d_out, flag);
}